// Round 6
// baseline (161.538 us; speedup 1.0000x reference)
//
#include <hip/hip_runtime.h>
#include <math.h>

// Capsule conv + dynamic routing via fp16 MFMA (16x16x32), swapped operands:
// A = prepped fp16 weights (M = f), B = fp16 input fragments (N = px).
// R17: ZERO-STAGING conv. R16's split showed routing-compute ~10-15us and a
// conv phase that is pure latency (MfmaUtil 9.4, VALUBusy 11, 116 unified
// regs -> 16-wave/CU cap) whose serial segments are the x-staging + barrier
// + LDS round trip. Fix: pre-convert x to a ZERO-PADDED fp16 tensor
// x16p[32][34][34][128] (9.5MB in d_ws, one streaming prep kernel). The MFMA
// B-fragment is 8 contiguous fp16 -> ONE global_load_dwordx4 straight from
// x16p: no patch LDS, no staging barrier, no bounds checks (padding absorbs
// the halo), no fp32->fp16 in the hot loop. Conv = 40 x (3 indep global b128
// + 2 MFMA), freely pipelined; block's 26KB x-window is L1-resident so the
// 8x c-wave B-redundancy hits L1. Routing unchanged (fused, R12 form).
// NOTE: hipLaunchCooperativeKernel is NOT graph-capturable here (R7 failed);
// ~44us d_ws re-poison fill + ~12us restore/launch are fixed harness overhead.
//
// x:    [B=32][H=32][W=32][128] fp32 (128 = i*16+cin)
// wts:  [i=8][k=144][o=128] fp32 -> w16[(i*5+q)][c][lane][j]
//       = wts[(i*144 + q*32 + (lane>>4)*8 + j)*128 + c*16 + (lane&15)], 0 for k>=144
// x16p: d_ws+512KB, fp16 [b][gh][gw][128], gh/gw in 0..33 = src -1..32, zero border
// out:  [B][H][W][128] fp32 (o = c*16+f)
//
// Block = 512 = 8 waves = c 0..7, full 32-px row; grid = 1024 (b*32+h).
// MFMA 16x16x32: A[m=lane&15 -> f][k=quad*8+j], B[k][n=lane&15 -> px(mt)].
// k = q*32 + quad*8 + j -> tap = 2q+(quad>>1) (clamped, A zero in pad),
// cin = (quad&1)*8 + j. B addr = x16p[b][h+dy][px+dx][i*16 + (quad&1)*8].
// D: px = mt*16 + lane&15, f = quad*4 + reg.

typedef _Float16 fp16x8 __attribute__((ext_vector_type(8)));
typedef float f32x4 __attribute__((ext_vector_type(4)));

#define EPS 1e-7f
constexpr int LSTRIDE = 76;    // lg_arr: [px*76 + i*9 + c]
constexpr int PXS     = 76;    // r_arr:  [px*76 + c*8 + i]; b128 stride 304B -> 2-way (free)
constexpr int W_ELEMS = 40 * 8 * 64 * 8;   // 163840
constexpr size_t X16P_OFF = 524288;        // bytes into d_ws (w16 ends at 327680)
constexpr int XP_CHUNKS = 32 * 34 * 34 * 16;  // 591872 8-elem chunks

// sum across the 4 quads (lanes ^16, ^32); all lanes receive the total
__device__ __forceinline__ float sumquad(float v) {
    v += __shfl_xor(v, 16);
    v += __shfl_xor(v, 32);
    return v;
}

// prep: direct scatter, 640 blocks x 256 threads, 1 element each (R8-proven).
__global__ __launch_bounds__(256)
void prep_weights(const float* __restrict__ wts,
                  _Float16* __restrict__ w16) {
    int n = blockIdx.x * 256 + threadIdx.x;        // 0..163839
    if (n >= W_ELEMS) return;
    int j    = n & 7;
    int ln   = (n >> 3) & 63;
    int c0   = (n >> 9) & 7;
    int iq   = n >> 12;                            // i*5+q
    int i0   = iq / 5;
    int q0   = iq - i0 * 5;
    int k = q0 * 32 + (ln >> 4) * 8 + j;
    float w = 0.f;
    if (k < 144) w = wts[(i0 * 144 + k) * 128 + c0 * 16 + (ln & 15)];
    w16[n] = (_Float16)w;                          // RNE
}

// prep: x fp32 -> zero-padded fp16 [32][34][34][128]. 2312 blocks x 256 thr,
// one 16B chunk (8 fp16) per thread; both sides fully coalesced.
__global__ __launch_bounds__(256)
void prep_x16(const float* __restrict__ x, _Float16* __restrict__ x16p) {
    int n8 = blockIdx.x * 256 + threadIdx.x;       // 0..591871 (exact)
    int chunk = n8 & 15;                           // 16 chunks of 8 per px
    int rest  = n8 >> 4;
    int gw    = rest % 34;
    int rest2 = rest / 34;
    int gh    = rest2 % 34;
    int b     = rest2 / 34;                        // 0..31
    _Float16 h8[8];
    if ((unsigned)(gh - 1) < 32u && (unsigned)(gw - 1) < 32u) {
        const float4* xs = (const float4*)x
            + ((((b * 32 + gh - 1) * 32) + gw - 1) << 5) + chunk * 2;
        float4 v0 = xs[0], v1 = xs[1];
        h8[0] = (_Float16)v0.x; h8[1] = (_Float16)v0.y;
        h8[2] = (_Float16)v0.z; h8[3] = (_Float16)v0.w;
        h8[4] = (_Float16)v1.x; h8[5] = (_Float16)v1.y;
        h8[6] = (_Float16)v1.z; h8[7] = (_Float16)v1.w;
    } else {
        #pragma unroll
        for (int t = 0; t < 8; ++t) h8[t] = (_Float16)0.f;
    }
    *(uint4*)(x16p + (size_t)n8 * 8) = *(const uint4*)h8;
}

__global__ __launch_bounds__(512, 4)
void capsule_mfma_kernel(const _Float16* __restrict__ x16p,
                         const _Float16* __restrict__ w16,
                         const float* __restrict__ bias,
                         float* __restrict__ out)
{
    __shared__ float lg_arr[32 * LSTRIDE];               // 9728 B
    __shared__ float r_arr[32 * PXS];                    // 9728 B

    const int tid  = threadIdx.x;
    const int lane = tid & 63;
    const int c    = tid >> 6;     // wave = c
    const int l15  = lane & 15;    // A: f ; B & D: px-in-tile
    const int quad = lane >> 4;
    const int lane8 = lane * 8;

    const int bid = blockIdx.x;
    const int h = bid & 31, b = bid >> 5;

    // ---- B per-lane element offsets into x16p (padded: no bounds checks) ----
    const _Float16* xb = x16p + (size_t)b * (34 * 34 * 128);
    int boff0[5], boff1[5];
    #pragma unroll
    for (int q = 0; q < 5; ++q) {
        int tap = 2 * q + (quad >> 1);
        if (tap > 8) tap = 8;                 // pad region: A is zero there
        int dy = tap / 3, dx = tap - dy * 3;
        int rowbase = (h + dy) * (34 * 128);
        boff0[q] = rowbase + (l15 + dx) * 128 + (quad & 1) * 8;
        boff1[q] = rowbase + (16 + l15 + dx) * 128 + (quad & 1) * 8;
    }

    // ---- conv via MFMA: 40 steps of (1 A + 2 B global b128, 2 MFMA) ----
    f32x4 acc[2][8];
    #pragma unroll
    for (int mt = 0; mt < 2; ++mt)
        #pragma unroll
        for (int i = 0; i < 8; ++i) acc[mt][i] = (f32x4){0.f, 0.f, 0.f, 0.f};

    #pragma unroll
    for (int q = 0; q < 5; ++q) {
        #pragma unroll
        for (int i = 0; i < 8; ++i) {
            int woff = ((i * 5 + q) * 8 + c) * 512 + lane8;
            fp16x8 aw = *(const fp16x8*)(w16 + woff);
            fp16x8 b0 = *(const fp16x8*)(xb + boff0[q] + i * 16);
            fp16x8 b1 = *(const fp16x8*)(xb + boff1[q] + i * 16);
            acc[0][i] = __builtin_amdgcn_mfma_f32_16x16x32_f16(aw, b0, acc[0][i], 0, 0, 0);
            acc[1][i] = __builtin_amdgcn_mfma_f32_16x16x32_f16(aw, b1, acc[1][i], 0, 0, 0);
        }
    }

    // ---- dynamic routing: thread owns (px = mt*16+l15, c, f = quad*4 + 0..3) ----
    const float4 bb4 = *(const float4*)(bias + c * 16 + quad * 4);
    const float barr[4] = {bb4.x, bb4.y, bb4.z, bb4.w};

    float actv[2][4];

    // iter 0: route = 1/8 uniform
    #pragma unroll
    for (int mt = 0; mt < 2; ++mt) {
        float pre[4];
        #pragma unroll
        for (int r = 0; r < 4; ++r) {
            float s = acc[mt][0][r] + acc[mt][1][r] + acc[mt][2][r] + acc[mt][3][r]
                    + acc[mt][4][r] + acc[mt][5][r] + acc[mt][6][r] + acc[mt][7][r];
            pre[r] = s * 0.125f + barr[r];
        }
        float s2 = sumquad(pre[0]*pre[0] + pre[1]*pre[1] + pre[2]*pre[2] + pre[3]*pre[3]);
        float scale = s2 * __builtin_amdgcn_rsqf(s2 + EPS) * __builtin_amdgcn_rcpf(1.f + s2);
        #pragma unroll
        for (int r = 0; r < 4; ++r) actv[mt][r] = scale * pre[r];
    }
    #pragma unroll
    for (int mt = 0; mt < 2; ++mt)
        #pragma unroll
        for (int i = 0; i < 8; ++i) {
            float t = acc[mt][i][0]*actv[mt][0] + acc[mt][i][1]*actv[mt][1]
                    + acc[mt][i][2]*actv[mt][2] + acc[mt][i][3]*actv[mt][3];
            t = sumquad(t);
            if (quad == 0) lg_arr[(mt * 16 + l15) * LSTRIDE + i * 9 + c] = t;
        }
    __syncthreads();
    if (tid < 256) {   // softmax over c for each (px, i)
        int p = tid >> 3, ii = tid & 7;
        const float* lrow = &lg_arr[p * LSTRIDE + ii * 9];
        float m = lrow[0];
        #pragma unroll
        for (int cc = 1; cc < 8; ++cc) m = fmaxf(m, lrow[cc]);
        float e[8]; float den = 0.f;
        #pragma unroll
        for (int cc = 0; cc < 8; ++cc) { e[cc] = __expf(lrow[cc] - m); den += e[cc]; }
        float rd = __builtin_amdgcn_rcpf(den);
        #pragma unroll
        for (int cc = 0; cc < 8; ++cc) r_arr[p * PXS + cc * 8 + ii] = e[cc] * rd;
    }
    __syncthreads();

    // iter 1
    #pragma unroll
    for (int mt = 0; mt < 2; ++mt) {
        const float4* rp = (const float4*)&r_arr[(mt * 16 + l15) * PXS + c * 8];
        float4 r0 = rp[0], r1 = rp[1];
        float pre[4];
        #pragma unroll
        for (int r = 0; r < 4; ++r) {
            float s;
            s  = r0.x * acc[mt][0][r]; s = fmaf(r0.y, acc[mt][1][r], s);
            s  = fmaf(r0.z, acc[mt][2][r], s); s = fmaf(r0.w, acc[mt][3][r], s);
            s  = fmaf(r1.x, acc[mt][4][r], s); s = fmaf(r1.y, acc[mt][5][r], s);
            s  = fmaf(r1.z, acc[mt][6][r], s); s = fmaf(r1.w, acc[mt][7][r], s);
            pre[r] = s + barr[r];
        }
        float s2 = sumquad(pre[0]*pre[0] + pre[1]*pre[1] + pre[2]*pre[2] + pre[3]*pre[3]);
        float scale = s2 * __builtin_amdgcn_rsqf(s2 + EPS) * __builtin_amdgcn_rcpf(1.f + s2);
        #pragma unroll
        for (int r = 0; r < 4; ++r) actv[mt][r] = scale * pre[r];
    }
    #pragma unroll
    for (int mt = 0; mt < 2; ++mt)
        #pragma unroll
        for (int i = 0; i < 8; ++i) {
            float t = acc[mt][i][0]*actv[mt][0] + acc[mt][i][1]*actv[mt][1]
                    + acc[mt][i][2]*actv[mt][2] + acc[mt][i][3]*actv[mt][3];
            t = sumquad(t);
            if (quad == 0) lg_arr[(mt * 16 + l15) * LSTRIDE + i * 9 + c] += t;
        }
    __syncthreads();
    if (tid < 256) {
        int p = tid >> 3, ii = tid & 7;
        const float* lrow = &lg_arr[p * LSTRIDE + ii * 9];
        float m = lrow[0];
        #pragma unroll
        for (int cc = 1; cc < 8; ++cc) m = fmaxf(m, lrow[cc]);
        float e[8]; float den = 0.f;
        #pragma unroll
        for (int cc = 0; cc < 8; ++cc) { e[cc] = __expf(lrow[cc] - m); den += e[cc]; }
        float rd = __builtin_amdgcn_rcpf(den);
        #pragma unroll
        for (int cc = 0; cc < 8; ++cc) r_arr[p * PXS + cc * 8 + ii] = e[cc] * rd;
    }
    __syncthreads();

    // iter 2: final activation -> out (per-lane float4: f = quad*4 + 0..3)
    #pragma unroll
    for (int mt = 0; mt < 2; ++mt) {
        const float4* rp = (const float4*)&r_arr[(mt * 16 + l15) * PXS + c * 8];
        float4 r0 = rp[0], r1 = rp[1];
        float pre[4];
        #pragma unroll
        for (int r = 0; r < 4; ++r) {
            float s;
            s  = r0.x * acc[mt][0][r]; s = fmaf(r0.y, acc[mt][1][r], s);
            s  = fmaf(r0.z, acc[mt][2][r], s); s = fmaf(r0.w, acc[mt][3][r], s);
            s  = fmaf(r1.x, acc[mt][4][r], s); s = fmaf(r1.y, acc[mt][5][r], s);
            s  = fmaf(r1.z, acc[mt][6][r], s); s = fmaf(r1.w, acc[mt][7][r], s);
            pre[r] = s + barr[r];
        }
        float s2 = sumquad(pre[0]*pre[0] + pre[1]*pre[1] + pre[2]*pre[2] + pre[3]*pre[3]);
        float scale = s2 * __builtin_amdgcn_rsqf(s2 + EPS) * __builtin_amdgcn_rcpf(1.f + s2);
        float4 o4 = { scale*pre[0], scale*pre[1], scale*pre[2], scale*pre[3] };
        int px = mt * 16 + l15;
        *(float4*)(out + (((b * 32 + h) * 32 + px) << 7) + c * 16 + quad * 4) = o4;
    }
}

extern "C" void kernel_launch(void* const* d_in, const int* in_sizes, int n_in,
                              void* d_out, int out_size, void* d_ws, size_t ws_size,
                              hipStream_t stream) {
    const float* x    = (const float*)d_in[0];
    const float* wts  = (const float*)d_in[1];
    const float* bias = (const float*)d_in[2];
    float* out        = (float*)d_out;
    _Float16* w16     = (_Float16*)d_ws;
    _Float16* x16p    = (_Float16*)((char*)d_ws + X16P_OFF);

    prep_weights<<<dim3(640), dim3(256), 0, stream>>>(wts, w16);
    prep_x16<<<dim3(XP_CHUNKS / 256), dim3(256), 0, stream>>>(x, x16p);
    capsule_mfma_kernel<<<dim3(1024), dim3(512), 0, stream>>>(x16p, w16, bias, out);
}

// Round 7
// 102.343 us; speedup vs baseline: 1.5784x; 1.5784x over previous
//
#include <hip/hip_runtime.h>
#include <math.h>

// Capsule conv + dynamic routing via fp16 MFMA (16x16x32), swapped operands:
// A = prepped fp16 weights (M = f), B = LDS input patch (N = px).
// R18: ONE-ROUND geometry. Evidence R12-R15: per-block time is a fixed
// ~21us latency chain (invariant to A-traffic, A-latency structure, and
// per-block WORK - R15 halved work, same time), and each CU ran 2 sequential
// rounds of 2 resident blocks -> 42us. R17 showed global-B is TA-bound
// (256B lane stride); B must stay in LDS. So: double px/block WITHOUT
// changing the per-thread economy: block = 1024 thr = 16 waves = (c 0..7) x
// (g 0..1), g = output row (h, h+1). Each wave runs the exact R12 per-wave
// program (40 x {1 A b128, 2 ds_read b128, 2 MFMA}, acc = 64 regs), taps
// shifted by g. Patch 4 rows x 34 cols = 37KB; LDS 75.9KB -> 2 blocks/CU;
// grid = 512 = ONE round. Waves (c,0)/(c,1) share A addresses -> L1 reuse.
// NOTE: hipLaunchCooperativeKernel is NOT graph-capturable here (R7 failed);
// ~44us d_ws re-poison fill + ~12us restore/launch are fixed harness overhead.
//
// x:    [B=32][H=32][W=32][128] fp32 (128 = i*16+cin)
// wts:  [i=8][k=144][o=128] fp32 -> w16[(i*5+q)][c][lane][j]
//       = wts[(i*144 + q*32 + (lane>>4)*8 + j)*128 + c*16 + (lane&15)], 0 for k>=144
// out:  [B][H][W][128] fp32 (o = c*16+f)
//
// Block = 1024 = 16 waves; wave w: c = w&7, g = w>>3; 2 rows x 32 px.
// Grid = 512 (b*16 + h2), h = 2*h2. Slot s = g*32 + mt*16 + l15 (0..63):
// output row = h+g, px-in-row = mt*16+l15.
// MFMA 16x16x32: A[m=lane&15 -> f][k=quad*8+j], B[k][n=lane&15 -> px(mt)].
// D: f = quad*4 + reg.

typedef _Float16 fp16x8 __attribute__((ext_vector_type(8)));
typedef float f32x4 __attribute__((ext_vector_type(4)));

#define EPS 1e-7f
constexpr int PSTRIDE = 136;   // fp16 elems; 272B row stride: 16B-aligned, 2-way banks (free)
constexpr int PCOLS   = 34;    // 32 px + 2 halo
constexpr int PROWS   = 4;     // rows h-1..h+2
constexpr int LSTRIDE = 76;    // lg_arr: [slot*76 + i*9 + c]
constexpr int PXS     = 76;    // r_arr:  [slot*76 + c*8 + i]; b128 stride 304B -> 2-way (free)
constexpr int W_ELEMS = 40 * 8 * 64 * 8;   // 163840

// sum across the 4 quads (lanes ^16, ^32); all lanes receive the total
__device__ __forceinline__ float sumquad(float v) {
    v += __shfl_xor(v, 16);
    v += __shfl_xor(v, 32);
    return v;
}

// prep: direct scatter, 640 blocks x 256 threads, 1 element each (R8-proven).
__global__ __launch_bounds__(256)
void prep_weights(const float* __restrict__ wts,
                  _Float16* __restrict__ w16) {
    int n = blockIdx.x * 256 + threadIdx.x;        // 0..163839
    if (n >= W_ELEMS) return;
    int j    = n & 7;
    int ln   = (n >> 3) & 63;
    int c0   = (n >> 9) & 7;
    int iq   = n >> 12;                            // i*5+q
    int i0   = iq / 5;
    int q0   = iq - i0 * 5;
    int k = q0 * 32 + (ln >> 4) * 8 + j;
    float w = 0.f;
    if (k < 144) w = wts[(i0 * 144 + k) * 128 + c0 * 16 + (ln & 15)];
    w16[n] = (_Float16)w;                          // RNE
}

__global__ __launch_bounds__(1024, 4)
void capsule_mfma_kernel(const float* __restrict__ x,
                         const _Float16* __restrict__ w16,
                         const float* __restrict__ bias,
                         float* __restrict__ out)
{
    __shared__ _Float16 patch[PROWS * PCOLS * PSTRIDE];  // 36992 B
    __shared__ float lg_arr[64 * LSTRIDE];               // 19456 B
    __shared__ float r_arr[64 * PXS];                    // 19456 B

    const int tid  = threadIdx.x;
    const int lane = tid & 63;
    const int w    = tid >> 6;     // 0..15
    const int c    = w & 7;        // output capsule
    const int g    = w >> 3;       // output row offset (0/1)
    const int l15  = lane & 15;    // A: f ; B & D: px-in-tile
    const int quad = lane >> 4;
    const int lane8 = lane * 8;

    const int bid = blockIdx.x;
    const int h2 = bid & 15, b = bid >> 4;
    const int h = h2 << 1;         // output rows h, h+1

    // ---- stage input patch rows h-1..h+2, cols -1..32, fp16 ----
    const float4* x4 = (const float4*)x;
    for (int idx = tid; idx < PROWS * PCOLS * 32; idx += 1024) {
        int ch4  = idx & 31;
        int slot = idx >> 5;               // row*34 + colp
        int row  = slot / PCOLS;
        int colp = slot - row * PCOLS;
        int gh = h - 1 + row;
        int gw = colp - 1;
        float4 v = {0.f, 0.f, 0.f, 0.f};
        if ((unsigned)gh < 32u && (unsigned)gw < 32u)
            v = x4[(((b * 32 + gh) * 32 + gw) << 5) + ch4];
        _Float16 ph[4];
        ph[0] = (_Float16)v.x; ph[1] = (_Float16)v.y;
        ph[2] = (_Float16)v.z; ph[3] = (_Float16)v.w;
        *(ushort4*)&patch[slot * PSTRIDE + ch4 * 4] = *(const ushort4*)ph;
    }
    __syncthreads();

    // ---- B (patch) per-lane offsets: k = q*32 + quad*8 + j; tap = 2q+(quad>>1) ----
    // output row h+g -> tap rows (g+dy)
    int a_off[5];
    #pragma unroll
    for (int q = 0; q < 5; ++q) {
        int tap = 2 * q + (quad >> 1);
        if (tap > 8) tap = 8;                 // pad region: A is zero there
        int dy = tap / 3, dx = tap - dy * 3;
        a_off[q] = ((g + dy) * PCOLS + l15 + dx) * PSTRIDE + (quad & 1) * 8;
    }

    // ---- conv via MFMA: 40 steps of (1 A b128 from L1/L2, 2 B ds_read, 2 MFMA) ----
    f32x4 acc[2][8];
    #pragma unroll
    for (int mt = 0; mt < 2; ++mt)
        #pragma unroll
        for (int i = 0; i < 8; ++i) acc[mt][i] = (f32x4){0.f, 0.f, 0.f, 0.f};

    #pragma unroll
    for (int q = 0; q < 5; ++q) {
        #pragma unroll
        for (int i = 0; i < 8; ++i) {
            int woff = ((i * 5 + q) * 8 + c) * 512 + lane8;
            fp16x8 aw = *(const fp16x8*)(w16 + woff);
            fp16x8 b0 = *(const fp16x8*)(patch + a_off[q] + i * 16);
            fp16x8 b1 = *(const fp16x8*)(patch + a_off[q] + 16 * PSTRIDE + i * 16);
            acc[0][i] = __builtin_amdgcn_mfma_f32_16x16x32_f16(aw, b0, acc[0][i], 0, 0, 0);
            acc[1][i] = __builtin_amdgcn_mfma_f32_16x16x32_f16(aw, b1, acc[1][i], 0, 0, 0);
        }
    }

    // ---- dynamic routing: thread owns (slot = g*32+mt*16+l15, c, f = quad*4+0..3) ----
    const float4 bb4 = *(const float4*)(bias + c * 16 + quad * 4);
    const float barr[4] = {bb4.x, bb4.y, bb4.z, bb4.w};

    float actv[2][4];

    // iter 0: route = 1/8 uniform
    #pragma unroll
    for (int mt = 0; mt < 2; ++mt) {
        float pre[4];
        #pragma unroll
        for (int r = 0; r < 4; ++r) {
            float s = acc[mt][0][r] + acc[mt][1][r] + acc[mt][2][r] + acc[mt][3][r]
                    + acc[mt][4][r] + acc[mt][5][r] + acc[mt][6][r] + acc[mt][7][r];
            pre[r] = s * 0.125f + barr[r];
        }
        float s2 = sumquad(pre[0]*pre[0] + pre[1]*pre[1] + pre[2]*pre[2] + pre[3]*pre[3]);
        float scale = s2 * __builtin_amdgcn_rsqf(s2 + EPS) * __builtin_amdgcn_rcpf(1.f + s2);
        #pragma unroll
        for (int r = 0; r < 4; ++r) actv[mt][r] = scale * pre[r];
    }
    #pragma unroll
    for (int mt = 0; mt < 2; ++mt) {
        int slot = g * 32 + mt * 16 + l15;
        #pragma unroll
        for (int i = 0; i < 8; ++i) {
            float t = acc[mt][i][0]*actv[mt][0] + acc[mt][i][1]*actv[mt][1]
                    + acc[mt][i][2]*actv[mt][2] + acc[mt][i][3]*actv[mt][3];
            t = sumquad(t);
            if (quad == 0) lg_arr[slot * LSTRIDE + i * 9 + c] = t;
        }
    }
    __syncthreads();
    if (tid < 512) {   // softmax over c for each (slot, i): 64*8 = 512 tasks
        int p = tid >> 3, ii = tid & 7;
        const float* lrow = &lg_arr[p * LSTRIDE + ii * 9];
        float m = lrow[0];
        #pragma unroll
        for (int cc = 1; cc < 8; ++cc) m = fmaxf(m, lrow[cc]);
        float e[8]; float den = 0.f;
        #pragma unroll
        for (int cc = 0; cc < 8; ++cc) { e[cc] = __expf(lrow[cc] - m); den += e[cc]; }
        float rd = __builtin_amdgcn_rcpf(den);
        #pragma unroll
        for (int cc = 0; cc < 8; ++cc) r_arr[p * PXS + cc * 8 + ii] = e[cc] * rd;
    }
    __syncthreads();

    // iter 1
    #pragma unroll
    for (int mt = 0; mt < 2; ++mt) {
        int slot = g * 32 + mt * 16 + l15;
        const float4* rp = (const float4*)&r_arr[slot * PXS + c * 8];
        float4 r0 = rp[0], r1 = rp[1];
        float pre[4];
        #pragma unroll
        for (int r = 0; r < 4; ++r) {
            float s;
            s  = r0.x * acc[mt][0][r]; s = fmaf(r0.y, acc[mt][1][r], s);
            s  = fmaf(r0.z, acc[mt][2][r], s); s = fmaf(r0.w, acc[mt][3][r], s);
            s  = fmaf(r1.x, acc[mt][4][r], s); s = fmaf(r1.y, acc[mt][5][r], s);
            s  = fmaf(r1.z, acc[mt][6][r], s); s = fmaf(r1.w, acc[mt][7][r], s);
            pre[r] = s + barr[r];
        }
        float s2 = sumquad(pre[0]*pre[0] + pre[1]*pre[1] + pre[2]*pre[2] + pre[3]*pre[3]);
        float scale = s2 * __builtin_amdgcn_rsqf(s2 + EPS) * __builtin_amdgcn_rcpf(1.f + s2);
        #pragma unroll
        for (int r = 0; r < 4; ++r) actv[mt][r] = scale * pre[r];
    }
    #pragma unroll
    for (int mt = 0; mt < 2; ++mt) {
        int slot = g * 32 + mt * 16 + l15;
        #pragma unroll
        for (int i = 0; i < 8; ++i) {
            float t = acc[mt][i][0]*actv[mt][0] + acc[mt][i][1]*actv[mt][1]
                    + acc[mt][i][2]*actv[mt][2] + acc[mt][i][3]*actv[mt][3];
            t = sumquad(t);
            if (quad == 0) lg_arr[slot * LSTRIDE + i * 9 + c] += t;
        }
    }
    __syncthreads();
    if (tid < 512) {
        int p = tid >> 3, ii = tid & 7;
        const float* lrow = &lg_arr[p * LSTRIDE + ii * 9];
        float m = lrow[0];
        #pragma unroll
        for (int cc = 1; cc < 8; ++cc) m = fmaxf(m, lrow[cc]);
        float e[8]; float den = 0.f;
        #pragma unroll
        for (int cc = 0; cc < 8; ++cc) { e[cc] = __expf(lrow[cc] - m); den += e[cc]; }
        float rd = __builtin_amdgcn_rcpf(den);
        #pragma unroll
        for (int cc = 0; cc < 8; ++cc) r_arr[p * PXS + cc * 8 + ii] = e[cc] * rd;
    }
    __syncthreads();

    // iter 2: final activation -> out (per-lane float4: f = quad*4 + 0..3)
    #pragma unroll
    for (int mt = 0; mt < 2; ++mt) {
        int slot = g * 32 + mt * 16 + l15;
        const float4* rp = (const float4*)&r_arr[slot * PXS + c * 8];
        float4 r0 = rp[0], r1 = rp[1];
        float pre[4];
        #pragma unroll
        for (int r = 0; r < 4; ++r) {
            float s;
            s  = r0.x * acc[mt][0][r]; s = fmaf(r0.y, acc[mt][1][r], s);
            s  = fmaf(r0.z, acc[mt][2][r], s); s = fmaf(r0.w, acc[mt][3][r], s);
            s  = fmaf(r1.x, acc[mt][4][r], s); s = fmaf(r1.y, acc[mt][5][r], s);
            s  = fmaf(r1.z, acc[mt][6][r], s); s = fmaf(r1.w, acc[mt][7][r], s);
            pre[r] = s + barr[r];
        }
        float s2 = sumquad(pre[0]*pre[0] + pre[1]*pre[1] + pre[2]*pre[2] + pre[3]*pre[3]);
        float scale = s2 * __builtin_amdgcn_rsqf(s2 + EPS) * __builtin_amdgcn_rcpf(1.f + s2);
        float4 o4 = { scale*pre[0], scale*pre[1], scale*pre[2], scale*pre[3] };
        int gh = h + g;
        int px = mt * 16 + l15;
        *(float4*)(out + (((b * 32 + gh) * 32 + px) << 7) + c * 16 + quad * 4) = o4;
    }
}

extern "C" void kernel_launch(void* const* d_in, const int* in_sizes, int n_in,
                              void* d_out, int out_size, void* d_ws, size_t ws_size,
                              hipStream_t stream) {
    const float* x    = (const float*)d_in[0];
    const float* wts  = (const float*)d_in[1];
    const float* bias = (const float*)d_in[2];
    float* out        = (float*)d_out;
    _Float16* w16     = (_Float16*)d_ws;

    prep_weights<<<dim3(640), dim3(256), 0, stream>>>(wts, w16);
    capsule_mfma_kernel<<<dim3(512), dim3(1024), 0, stream>>>(x, w16, bias, out);
}